// Round 10
// baseline (246.418 us; speedup 1.0000x reference)
//
#include <hip/hip_runtime.h>
#include <hip/hip_bf16.h>
#include <math.h>

#define Bq 8
#define Tq 2048
#define Dq 2048
#define Rq 4
#define Mq (Bq*Tq)      // 16384
#define NC 16           // scan chunks
#define CL (Tq/NC)      // 128 timesteps per chunk

typedef __attribute__((ext_vector_type(8))) short bf16x8;
typedef __attribute__((ext_vector_type(4))) float f32x4;
typedef __attribute__((ext_vector_type(16))) float f32x16;
typedef __attribute__((ext_vector_type(4))) unsigned short us4;
typedef __attribute__((ext_vector_type(8))) unsigned short us8;

__device__ __forceinline__ unsigned short f2bf(float x) {
    unsigned int u = __float_as_uint(x);
    unsigned int r = (u + 0x7fffu + ((u >> 16) & 1u)) >> 16;   // RNE
    return (unsigned short)r;
}
__device__ __forceinline__ float bf2f(unsigned short h) {
    return __uint_as_float((unsigned)h << 16);
}

template<int UGBF>
__device__ __forceinline__ f32x4 ld4(const void* p, long long off) {
    if constexpr (UGBF) {
        us4 v = *(const us4*)((const unsigned short*)p + off);
        f32x4 r;
        r.x = bf2f(v.x); r.y = bf2f(v.y); r.z = bf2f(v.z); r.w = bf2f(v.w);
        return r;
    } else {
        return *(const f32x4*)((const float*)p + off);
    }
}

// ---------------- K0: convert u, gate_w to bf16; build aa power tables ------
__global__ __launch_bounds__(256) void k0_convert(
    const float* __restrict__ u, const float* __restrict__ gw,
    const float* __restrict__ a,
    unsigned short* __restrict__ ubf, unsigned short* __restrict__ wbf,
    float* __restrict__ aat, float* __restrict__ aaLt,
    float* __restrict__ aapow)
{
    const long long uN4 = (long long)Mq * Dq / 4;
    const long long wN4 = (long long)Dq * Dq / 4;
    long long gid = (long long)blockIdx.x * blockDim.x + threadIdx.x;
    if (gid < Dq) {
        float aa = tanhf(a[gid]);
        aat[gid] = aa;
        aaLt[gid] = exp2f((float)CL * log2f(aa));
        float p = 1.0f;
        for (int k = 0; k <= 16; ++k) { aapow[k * Dq + gid] = p; p *= aa; }
    }
    long long stride = (long long)gridDim.x * blockDim.x;
    for (long long i = gid; i < uN4 + wN4; i += stride) {
        const float4* src; unsigned short* dst; long long j;
        if (i < uN4) { src = (const float4*)u;  dst = ubf; j = i; }
        else         { src = (const float4*)gw; dst = wbf; j = i - uN4; }
        float4 v = src[j];
        us4 p;
        p.x = f2bf(v.x); p.y = f2bf(v.y); p.z = f2bf(v.z); p.w = f2bf(v.w);
        *(us4*)(dst + j * 4) = p;
    }
}

// ---------------- K1: 256x256 4-phase 32x32x16 MFMA GEMM + fused epilogue ---
// BM=BN=256, BK=64, 512 thr = 8 waves (2M x 4N), per-wave out 128x64.
// 32x32x16 MFMA: A/B frag = lane holds [row|col = l&31][k = (l>>5)*8+j].
// 2 phases per K-tile: P={LDA m-pair (8 rd) [+LDB both n (8 rd)]; 2xSTAGE2;
//   BAR; 16 MFMA (4 indep chains, dist 4); BAR}. vmcnt(4) at P2/P4 drains
//   loads aged >= 1 mega-phase. C/D: col=l&31, row=(r&3)+8(r>>2)+4(l>>5).

#define PH_BAR __builtin_amdgcn_s_barrier()
#define PRIO1  __builtin_amdgcn_s_setprio(1)
#define PRIO0  __builtin_amdgcn_s_setprio(0)

#define LDA32(BUF, mb) do { _Pragma("unroll") for (int s_ = 0; s_ < 4; ++s_) { \
    aF[s_][0] = *(const bf16x8*)&lds[kA[s_] + (BUF) + (mb) * 2048]; \
    aF[s_][1] = *(const bf16x8*)&lds[kA[s_] + (BUF) + ((mb) + 1) * 2048]; } } while (0)

#define LDB32(BUF) do { _Pragma("unroll") for (int s_ = 0; s_ < 4; ++s_) { \
    bF[s_][0] = *(const bf16x8*)&lds[kB[s_] + (BUF)]; \
    bF[s_][1] = *(const bf16x8*)&lds[kB[s_] + (BUF) + 2048]; } } while (0)

#define MMA2x2(mb) do { _Pragma("unroll") for (int s_ = 0; s_ < 4; ++s_) { \
    acc[(mb)][0]     = __builtin_amdgcn_mfma_f32_32x32x16_bf16(aF[s_][0], bF[s_][0], acc[(mb)][0],     0, 0, 0); \
    acc[(mb)][1]     = __builtin_amdgcn_mfma_f32_32x32x16_bf16(aF[s_][0], bF[s_][1], acc[(mb)][1],     0, 0, 0); \
    acc[(mb) + 1][0] = __builtin_amdgcn_mfma_f32_32x32x16_bf16(aF[s_][1], bF[s_][0], acc[(mb) + 1][0], 0, 0, 0); \
    acc[(mb) + 1][1] = __builtin_amdgcn_mfma_f32_32x32x16_bf16(aF[s_][1], bF[s_][1], acc[(mb) + 1][1], 0, 0, 0); } } while (0)

#define GLD(P, DST) __builtin_amdgcn_global_load_lds( \
    (const __attribute__((address_space(1))) void*)(P), \
    (__attribute__((address_space(3))) void*)&lds[DST], 16, 0, 0)

#define STAGE2(P0, P1, DBASE, KOFF) do { \
    GLD((P0) + (KOFF), (DBASE));         \
    GLD((P1) + (KOFF), (DBASE) + 512); } while (0)

template<int UGBF>
__global__ __launch_bounds__(512, 2) void k1_gemm(
    const unsigned short* __restrict__ Abf,   // u   [M][K] bf16
    const unsigned short* __restrict__ Bbf,   // gw  [N][K] bf16 (B^T layout)
    const float* __restrict__ gate_b,         // [D]
    const float* __restrict__ bvec,           // [D]
    const float* __restrict__ aapow,          // [17][D]: aa^k
    float* __restrict__ psum,                 // [B][NC][D]
    float* __restrict__ carry,                // [B][NC][D]
    void* __restrict__ ug_)                   // out: u_g [M][D] (bf16 or f32)
{
    __shared__ unsigned short lds[65536];     // 128 KiB
    const int tid  = threadIdx.x;
    const int wave = tid >> 6, lane = tid & 63;
    const int wr = wave >> 2, wc = wave & 3;  // 2M x 4N waves

    const int bid = blockIdx.x;
    const int swz = (bid & 7) * 64 + (bid >> 3);   // XCD swizzle, 512 % 8 == 0
    const int tm = (swz >> 3) * 256;
    const int tn = (swz & 7) * 256;

    const int l31 = lane & 31, hi = lane >> 5, s7 = lane & 7;

    // swizzled LDS read bases per k-frag s: slot = 2s+hi, swz slot ^= row&7
    int kA[4], kB[4];
    {
        const int aR = wr * 8192 + l31 * 64;
        const int bR = 16384 + (wc >> 1) * 8192 + (wc & 1) * 4096 + l31 * 64;
#pragma unroll
        for (int s = 0; s < 4; ++s) {
            const int ko = ((2 * s + hi) ^ s7) * 8;
            kA[s] = aR + ko;
            kB[s] = bR + ko;
        }
    }

    // stage source pointers: lane covers row (lane>>3), perm'd 16B slot
    const int grow  = lane >> 3;              // 0..7
    const int gslot = ((lane & 7) ^ grow) * 8;
    const unsigned short* gA00 = Abf + (long long)(tm + wave * 16 + grow) * Dq + gslot;
    const unsigned short* gA01 = gA00 + 8 * Dq;
    const unsigned short* gA10 = gA00 + 128 * Dq;
    const unsigned short* gA11 = gA00 + 136 * Dq;
    const unsigned short* gB00 = Bbf + (long long)(tn + wave * 16 + grow) * Dq + gslot;
    const unsigned short* gB01 = gB00 + 8 * Dq;
    const unsigned short* gB10 = gB00 + 128 * Dq;
    const unsigned short* gB11 = gB00 + 136 * Dq;

    f32x16 acc[4][2] = {};
    bf16x8 aF[4][2], bF[4][2];

    const int dA0 = wave * 1024;              // A dest base, dbuf0
    const int dB0 = 16384 + wave * 1024;      // B dest base, dbuf0

    // prologue: buf0 A+B (K-tile 0), buf1 B (K-tile 1); buf1-A staged in P1
    STAGE2(gA00, gA01, dA0,                0);
    STAGE2(gA10, gA11, dA0 + 8192,         0);
    STAGE2(gB00, gB01, dB0,                0);
    STAGE2(gB10, gB11, dB0 + 8192,         0);
    STAGE2(gB00, gB01, dB0 + 32768,        64);
    STAGE2(gB10, gB11, dB0 + 32768 + 8192, 64);
    asm volatile("s_waitcnt vmcnt(4)" ::: "memory");
    PH_BAR;

    const int NIT = Dq / 128;                 // 16 iters, 2 K-tiles each
    for (int it = 0; it < NIT; ++it) {
        const bool pre = (it < NIT - 1);

        // ---- P1: K-even (buf0), m-pair 0 x both n ----
        LDA32(0, 0); LDB32(0);
        STAGE2(gA00, gA01, dA0 + 32768, 64);             // buf1-A h0 (this iter)
        STAGE2(gA10, gA11, dA0 + 32768 + 8192, 64);      // buf1-A h1
        asm volatile("s_waitcnt lgkmcnt(8)" ::: "memory");
        PH_BAR; PRIO1; MMA2x2(0); PRIO0; PH_BAR;

        // ---- P2: K-even (buf0), m-pair 2 ----
        LDA32(0, 2);
        if (pre) {
            STAGE2(gB00, gB01, dB0, 128);                // buf0-B next, h0
            STAGE2(gB10, gB11, dB0 + 8192, 128);         // buf0-B next, h1
            asm volatile("s_waitcnt vmcnt(4)" ::: "memory");   // drains buf1-A
        } else {
            asm volatile("s_waitcnt vmcnt(0)" ::: "memory");
        }
        PH_BAR; PRIO1; MMA2x2(2); PRIO0; PH_BAR;

        // ---- P3: K-odd (buf1), m-pair 0 x both n ----
        LDA32(32768, 0); LDB32(32768);
        if (pre) {
            STAGE2(gA00, gA01, dA0, 128);                // buf0-A next, h0
            STAGE2(gA10, gA11, dA0 + 8192, 128);         // buf0-A next, h1
        }
        asm volatile("s_waitcnt lgkmcnt(8)" ::: "memory");
        PH_BAR; PRIO1; MMA2x2(0); PRIO0; PH_BAR;

        // ---- P4: K-odd (buf1), m-pair 2 ----
        LDA32(32768, 2);
        if (pre) {
            STAGE2(gB00, gB01, dB0 + 32768, 192);        // buf1-B next, h0
            STAGE2(gB10, gB11, dB0 + 32768 + 8192, 192); // buf1-B next, h1
            asm volatile("s_waitcnt vmcnt(4)" ::: "memory");   // drains buf0 next A+B
        }
        PH_BAR; PRIO1; MMA2x2(2); PRIO0; PH_BAR;

        gA00 += 128; gA01 += 128; gA10 += 128; gA11 += 128;
        gB00 += 128; gB01 += 128; gB10 += 128; gB11 += 128;
    }

    // ---- epilogue phase A: sigmoid -> LDS (bf16, col ^ ((row>>2)&3)<<4) ----
    // 32x32 C/D: col = wc*64 + nf*32 + l31; row = wr*128+mf*32+(r&3)+8(r>>2)+4*hi
#pragma unroll
    for (int nf = 0; nf < 2; ++nf) {
        const int col = wc * 64 + nf * 32 + l31;
        const float gb = gate_b[tn + col];
#pragma unroll
        for (int mf = 0; mf < 4; ++mf) {
#pragma unroll
            for (int r = 0; r < 16; ++r) {
                const int row = wr * 128 + mf * 32 + (r & 3) + 8 * (r >> 2) + 4 * hi;
                const int xsw = (((2 * (r >> 2) + hi)) & 3) << 4;   // ((row>>2)&3)<<4
                const float logit = acc[mf][nf][r] + gb;
                const float sg = 1.0f / (1.0f + __expf(-logit));
                lds[row * 256 + (col ^ xsw)] = f2bf(sg);
            }
        }
    }
    __syncthreads();

    // ---- epilogue phase B: coalesced u_g + fused per-chunk scan partials ---
    const int lr2  = lane >> 5;               // 0/1
    const int cb32 = lane & 31;
    const int c0   = cb32 * 8;                // 8-col segment
    const int baseT = wave * 2 + lr2;         // 0..15: row offset within 16
    const int cX = ((baseT >> 2) & 3) << 4;   // constant swizzle for this thread

    float bw[8], a16[8], w15[8];
    {
        const float* bp   = bvec + tn + c0;
        const float* a16p = aapow + 16 * Dq + tn + c0;
        const float* w15p = aapow + (15 - baseT) * Dq + tn + c0;
#pragma unroll
        for (int k = 0; k < 8; ++k) { bw[k] = bp[k]; a16[k] = a16p[k]; w15[k] = w15p[k]; }
    }

    float ps[2][8] = {}, cr[2][8] = {};
#pragma unroll
    for (int i = 0; i < 16; ++i) {
        const int r = baseT + i * 16;         // row in tile
        const int ck = i >> 3;                // local chunk (0/1)
        const long long gidx = (long long)(tm + r) * Dq + tn + c0;
        const bf16x8 u8 = *(const bf16x8*)&Abf[gidx];
        const bf16x8 s8 = *(const bf16x8*)&lds[r * 256 + (c0 ^ cX)];
        float ug[8];
#pragma unroll
        for (int k = 0; k < 8; ++k) {
            ug[k] = bf2f((unsigned short)u8[k]) * bf2f((unsigned short)s8[k]);
            ps[ck][k] += ug[k];
            cr[ck][k] = a16[k] * cr[ck][k] + bw[k] * ug[k];
        }
        if constexpr (UGBF) {
            us8 o;
#pragma unroll
            for (int k = 0; k < 8; ++k) o[k] = f2bf(ug[k]);
            *(us8*)&((unsigned short*)ug_)[gidx] = o;
        } else {
            f32x4 o0, o1;
            o0.x = ug[0]; o0.y = ug[1]; o0.z = ug[2]; o0.w = ug[3];
            o1.x = ug[4]; o1.y = ug[5]; o1.z = ug[6]; o1.w = ug[7];
            *(f32x4*)&((float*)ug_)[gidx]     = o0;
            *(f32x4*)&((float*)ug_)[gidx + 4] = o1;
        }
    }
    __syncthreads();                           // all sigma reads done

    // deterministic 16-slot tree reduce in LDS: red[p:4][col:256][slot:16] f32
    float* redf = (float*)lds;
    const int slot = (baseT + cb32) & 15;      // rotation: col>>3 == cb32
#pragma unroll
    for (int ck = 0; ck < 2; ++ck)
#pragma unroll
        for (int k = 0; k < 8; ++k) {
            const int col = c0 + k;
            redf[((ck * 2 + 0) * 256 + col) * 16 + slot] = ps[ck][k];
            redf[((ck * 2 + 1) * 256 + col) * 16 + slot] = cr[ck][k] * w15[k];
        }
    __syncthreads();

    const int bb  = tm >> 11;                  // batch index
    const int ckb = (tm & 2047) >> 7;          // global chunk base
#pragma unroll
    for (int ii = 0; ii < 2; ++ii) {
        const int item = tid + ii * 512;       // 1024 items = 4 groups x 256 cols
        const int p = item >> 8, col = item & 255;
        const int ck = p >> 1, isC = p & 1;
        const int rot = (item & 3) * 4;
        float s = 0.f;
#pragma unroll
        for (int q = 0; q < 4; ++q) {
            const f32x4 v = *(const f32x4*)&redf[item * 16 + ((rot + q * 4) & 15)];
            s += v.x + v.y + v.z + v.w;
        }
        const long long gi = (long long)(bb * NC + ckb + ck) * Dq + tn + col;
        if (isC) carry[gi] = s; else psum[gi] = s;
    }
}

// ---------------- K3: mean -> rank-4 projection -> d_eff --------------------
__global__ __launch_bounds__(256) void k3_deff(
    const float* __restrict__ psum, const float* __restrict__ dvec,
    const float* __restrict__ dlru, const float* __restrict__ dlrv,
    float* __restrict__ deff)
{
    const int bb = blockIdx.x, tid = threadIdx.x;
    __shared__ float red[4][256];
    __shared__ float proj[4];
    float pr[4] = {0.f, 0.f, 0.f, 0.f};
    for (int i = 0; i < Dq / 256; ++i) {
        int dd = tid + i * 256;
        float m = 0.f;
        for (int k = 0; k < NC; ++k) m += psum[((long long)bb * NC + k) * Dq + dd];
        m *= (1.0f / (float)Tq);
#pragma unroll
        for (int r = 0; r < 4; ++r) pr[r] += m * dlru[dd * Rq + r];
    }
#pragma unroll
    for (int r = 0; r < 4; ++r) red[r][tid] = pr[r];
    __syncthreads();
    for (int off = 128; off > 0; off >>= 1) {
        if (tid < off)
#pragma unroll
            for (int r = 0; r < 4; ++r) red[r][tid] += red[r][tid + off];
        __syncthreads();
    }
    if (tid < 4) proj[tid] = red[tid][0] * 0.25f;
    __syncthreads();
    float p0 = proj[0], p1 = proj[1], p2 = proj[2], p3 = proj[3];
    for (int i = 0; i < Dq / 256; ++i) {
        int e = tid + i * 256;
        float v = dvec[e] + p0 * dlrv[0 * Dq + e] + p1 * dlrv[1 * Dq + e]
                          + p2 * dlrv[2 * Dq + e] + p3 * dlrv[3 * Dq + e];
        deff[(long long)bb * Dq + e] = v;
    }
}

// ---------------- K4: scan pass C — combine carries, rescan, write y --------
template<int UGBF>
__global__ __launch_bounds__(128) void k4_scanC(
    const void* __restrict__ ug, float* __restrict__ yout,
    const float* __restrict__ aat, const float* __restrict__ aaLt,
    const float* __restrict__ bvec, const float* __restrict__ cvec,
    const float* __restrict__ deff, const float* __restrict__ carry)
{
    const int d0 = blockIdx.x * 512 + threadIdx.x * 4;
    const int ck = blockIdx.y, bb = blockIdx.z;
    f32x4 aa  = *(const f32x4*)&aat[d0];
    f32x4 aaL = *(const f32x4*)&aaLt[d0];
    f32x4 bv  = *(const f32x4*)&bvec[d0];
    f32x4 cv  = *(const f32x4*)&cvec[d0];
    f32x4 de  = *(const f32x4*)&deff[(long long)bb * Dq + d0];
    f32x4 s = {0.f, 0.f, 0.f, 0.f};
    for (int j = 0; j < ck; ++j) {
        f32x4 cj = *(const f32x4*)&carry[((long long)bb * NC + j) * Dq + d0];
        s = aaL * s + cj;
    }
    const long long base = ((long long)bb * Tq + (long long)ck * CL) * Dq + d0;
    for (int t = 0; t < CL; ++t) {
        f32x4 x = ld4<UGBF>(ug, base + (long long)t * Dq);
        s = aa * s + bv * x;
        f32x4 y = cv * s + de * x;
        *(f32x4*)&yout[base + (long long)t * Dq] = y;
    }
}

extern "C" void kernel_launch(void* const* d_in, const int* in_sizes, int n_in,
                              void* d_out, int out_size, void* d_ws, size_t ws_size,
                              hipStream_t stream)
{
    const float* u    = (const float*)d_in[0];
    const float* a    = (const float*)d_in[1];
    const float* b    = (const float*)d_in[2];
    const float* c    = (const float*)d_in[3];
    const float* d    = (const float*)d_in[4];
    const float* gw   = (const float*)d_in[5];
    const float* gb   = (const float*)d_in[6];
    const float* dlru = (const float*)d_in[7];
    const float* dlrv = (const float*)d_in[8];
    float* out = (float*)d_out;

    char* ws = (char*)d_ws;
    const size_t sz_ubf = (size_t)Mq * Dq * 2;          // 64 MiB
    const size_t sz_wbf = (size_t)Dq * Dq * 2;          // 8 MiB
    const size_t sz_ug  = (size_t)Mq * Dq * 2;          // 64 MiB (bf16 u_g)
    const size_t sz_ps  = (size_t)Bq * NC * Dq * 4;     // 1 MiB each

    unsigned short* ubf = (unsigned short*)ws;
    unsigned short* wbf = (unsigned short*)(ws + sz_ubf);

    const size_t tail_sz = 2 * sz_ps + (size_t)Bq * Dq * 4
                         + 2 * (size_t)Dq * 4 + (size_t)17 * Dq * 4;
    const size_t need_bf16 = sz_ubf + sz_wbf + sz_ug + tail_sz;
    const bool ugbf_mode = (ws_size >= need_bf16);

    char* rest = ws + sz_ubf + sz_wbf;
    unsigned short* ugbf = (unsigned short*)rest;
    char* tail = ugbf_mode ? (rest + sz_ug) : rest;
    float* psum  = (float*)tail;
    float* carry = psum  + (size_t)Bq * NC * Dq;
    float* deff  = carry + (size_t)Bq * NC * Dq;
    float* aat   = deff  + (size_t)Bq * Dq;
    float* aaLt  = aat   + Dq;
    float* aapow = aaLt  + Dq;                          // [17][Dq]

    k0_convert<<<2048, 256, 0, stream>>>(u, gw, a, ubf, wbf, aat, aaLt, aapow);

    dim3 g2(Dq / 512, NC, Bq);
    if (ugbf_mode) {
        k1_gemm<1><<<512, 512, 0, stream>>>(ubf, wbf, gb, b, aapow, psum, carry, ugbf);
        k3_deff<<<Bq, 256, 0, stream>>>(psum, d, dlru, dlrv, deff);
        k4_scanC<1><<<g2, 128, 0, stream>>>(ugbf, out, aat, aaLt, b, c, deff, carry);
    } else {
        k1_gemm<0><<<512, 512, 0, stream>>>(ubf, wbf, gb, b, aapow, psum, carry, out);
        k3_deff<<<Bq, 256, 0, stream>>>(psum, d, dlru, dlrv, deff);
        k4_scanC<0><<<g2, 128, 0, stream>>>(out, out, aat, aaLt, b, c, deff, carry);
    }
}

// Round 11
// 232.475 us; speedup vs baseline: 1.0600x; 1.0600x over previous
//
#include <hip/hip_runtime.h>
#include <hip/hip_bf16.h>
#include <math.h>

#define Bq 8
#define Tq 2048
#define Dq 2048
#define Rq 4
#define Mq (Bq*Tq)      // 16384
#define NC 16           // scan chunks
#define CL (Tq/NC)      // 128 timesteps per chunk

typedef __attribute__((ext_vector_type(8))) short bf16x8;
typedef __attribute__((ext_vector_type(4))) float f32x4;
typedef __attribute__((ext_vector_type(4))) unsigned short us4;
typedef __attribute__((ext_vector_type(8))) unsigned short us8;

__device__ __forceinline__ unsigned short f2bf(float x) {
    unsigned int u = __float_as_uint(x);
    unsigned int r = (u + 0x7fffu + ((u >> 16) & 1u)) >> 16;   // RNE
    return (unsigned short)r;
}
__device__ __forceinline__ float bf2f(unsigned short h) {
    return __uint_as_float((unsigned)h << 16);
}

template<int UGBF>
__device__ __forceinline__ f32x4 ld4(const void* p, long long off) {
    if constexpr (UGBF) {
        us4 v = *(const us4*)((const unsigned short*)p + off);
        f32x4 r;
        r.x = bf2f(v.x); r.y = bf2f(v.y); r.z = bf2f(v.z); r.w = bf2f(v.w);
        return r;
    } else {
        return *(const f32x4*)((const float*)p + off);
    }
}

// ---------------- K0: convert u, gate_w to bf16; build aa power tables ------
__global__ __launch_bounds__(256) void k0_convert(
    const float* __restrict__ u, const float* __restrict__ gw,
    const float* __restrict__ a,
    unsigned short* __restrict__ ubf, unsigned short* __restrict__ wbf,
    float* __restrict__ aat, float* __restrict__ aaLt,
    float* __restrict__ aapow)
{
    const long long uN4 = (long long)Mq * Dq / 4;
    const long long wN4 = (long long)Dq * Dq / 4;
    long long gid = (long long)blockIdx.x * blockDim.x + threadIdx.x;
    if (gid < Dq) {
        float aa = tanhf(a[gid]);
        aat[gid] = aa;
        aaLt[gid] = exp2f((float)CL * log2f(aa));
        float p = 1.0f;
        for (int k = 0; k <= 16; ++k) { aapow[k * Dq + gid] = p; p *= aa; }
    }
    long long stride = (long long)gridDim.x * blockDim.x;
    for (long long i = gid; i < uN4 + wN4; i += stride) {
        const float4* src; unsigned short* dst; long long j;
        if (i < uN4) { src = (const float4*)u;  dst = ubf; j = i; }
        else         { src = (const float4*)gw; dst = wbf; j = i - uN4; }
        float4 v = src[j];
        us4 p;
        p.x = f2bf(v.x); p.y = f2bf(v.y); p.z = f2bf(v.z); p.w = f2bf(v.w);
        *(us4*)(dst + j * 4) = p;
    }
}

// ---------------- K1: 256x256 8-phase bf16 MFMA GEMM + fused epilogue -------
// BM=BN=256, BK=64, 512 thr = 8 waves (2M x 4N), per-wave out 128x64.
// VERIFIED BEST (R9 = R7 config, 154.4 us, MfmaUtil 39%). Session ledger:
//  - R5 ks-reorder: null. R6 128B-row geometry: null. R7 aged vmcnt(4): +7us.
//  - R8 reg-staged A (f32->cvt->ds_write in-loop): -40us REGRESSION (extra
//    fetch + LDS-pipe writes + young vmcnt). Reverted.
//  - R10 32x32x16 frags: -7us REGRESSION (lanes {l,l+8,l+16,l+24} share
//    s7 -> same XOR slot -> 4-way bank conflict, 1.3e7 counts). Reverted.
// Cycle model/K-tile/CU: MFMA 2484 + LDS-rd 1536 + stage-wr 256 + sync ~1500
// = 5813 measured; loss is phase serialization, not LDS BW. m201's counted-
// vmcnt overlap not reproducible from spec here (learn_hip m232: port OPEN).

#define PH_BAR __builtin_amdgcn_s_barrier()
#define PRIO1  __builtin_amdgcn_s_setprio(1)
#define PRIO0  __builtin_amdgcn_s_setprio(0)

#define LDA(K0, K1, qb) do { _Pragma("unroll") for (int f_ = 0; f_ < 4; ++f_) { \
    aF[0][f_] = *(const bf16x8*)&lds[(K0) + ((qb) + f_) * 1024]; \
    aF[1][f_] = *(const bf16x8*)&lds[(K1) + ((qb) + f_) * 1024]; } } while (0)

#define LDB(K0, K1, fnb) do { _Pragma("unroll") for (int f_ = 0; f_ < 2; ++f_) { \
    bF[0][(fnb) + f_] = *(const bf16x8*)&lds[(K0) + ((fnb) + f_) * 1024]; \
    bF[1][(fnb) + f_] = *(const bf16x8*)&lds[(K1) + ((fnb) + f_) * 1024]; } } while (0)

#define MMA(fmb, fnb) do { _Pragma("unroll") for (int ks_ = 0; ks_ < 2; ++ks_) \
    _Pragma("unroll") for (int fm_ = 0; fm_ < 4; ++fm_) \
    _Pragma("unroll") for (int fn_ = 0; fn_ < 2; ++fn_) \
        acc[(fmb) + fm_][(fnb) + fn_] = __builtin_amdgcn_mfma_f32_16x16x32_bf16( \
            aF[ks_][fm_], bF[ks_][(fnb) + fn_], acc[(fmb) + fm_][(fnb) + fn_], 0, 0, 0); } while (0)

#define GLD(P, DST) __builtin_amdgcn_global_load_lds( \
    (const __attribute__((address_space(1))) void*)(P), \
    (__attribute__((address_space(3))) void*)&lds[DST], 16, 0, 0)

// stage one operand-half: 2 GLD (row-pairs P0 rows +0..7, P1 rows +8..15)
#define STAGE2(P0, P1, DBASE, KOFF) do { \
    GLD((P0) + (KOFF), (DBASE));         \
    GLD((P1) + (KOFF), (DBASE) + 512); } while (0)

template<int UGBF>
__global__ __launch_bounds__(512, 2) void k1_gemm(
    const unsigned short* __restrict__ Abf,   // u   [M][K] bf16
    const unsigned short* __restrict__ Bbf,   // gw  [N][K] bf16 (B^T layout)
    const float* __restrict__ gate_b,         // [D]
    const float* __restrict__ bvec,           // [D]
    const float* __restrict__ aapow,          // [17][D]: aa^k
    float* __restrict__ psum,                 // [B][NC][D]
    float* __restrict__ carry,                // [B][NC][D]
    void* __restrict__ ug_)                   // out: u_g [M][D] (bf16 or f32)
{
    __shared__ unsigned short lds[65536];     // 128 KiB
    const int tid  = threadIdx.x;
    const int wave = tid >> 6, lane = tid & 63;
    const int wr = wave >> 2, wc = wave & 3;  // 2M x 4N waves

    const int bid = blockIdx.x;
    const int swz = (bid & 7) * 64 + (bid >> 3);   // XCD swizzle, 512 % 8 == 0
    const int tm = (swz >> 3) * 256;
    const int tn = (swz & 7) * 256;

    const int rr = lane & 15, kq = lane >> 4;
    const int r7 = rr & 7;
    const int kb0 = (kq ^ r7) * 8;            // ks=0 swizzled 16B-slot
    const int kb1 = ((4 + kq) ^ r7) * 8;      // ks=1

    // hoisted swizzled LDS read bases (ushort units)
    const int aB = wr * 8192 + rr * 64;
    const int bB = 16384 + (wc >> 1) * 8192 + (wc & 1) * 4096 + rr * 64;
    const int swA0k0 = aB + kb0,          swA0k1 = aB + kb1;
    const int swA1k0 = aB + 32768 + kb0,  swA1k1 = aB + 32768 + kb1;
    const int swB0k0 = bB + kb0,          swB0k1 = bB + kb1;
    const int swB1k0 = bB + 32768 + kb0,  swB1k1 = bB + 32768 + kb1;

    // stage source pointers: lane covers row (lane>>3), perm'd 16B slot
    const int grow  = lane >> 3;              // 0..7
    const int gslot = ((lane & 7) ^ grow) * 8;
    const unsigned short* gA00 = Abf + (long long)(tm + wave * 16 + grow) * Dq + gslot;
    const unsigned short* gA01 = gA00 + 8 * Dq;
    const unsigned short* gA10 = gA00 + 128 * Dq;
    const unsigned short* gA11 = gA00 + 136 * Dq;
    const unsigned short* gB00 = Bbf + (long long)(tn + wave * 16 + grow) * Dq + gslot;
    const unsigned short* gB01 = gB00 + 8 * Dq;
    const unsigned short* gB10 = gB00 + 128 * Dq;
    const unsigned short* gB11 = gB00 + 136 * Dq;

    f32x4 acc[8][4] = {};
    bf16x8 aF[2][4], bF[2][4];

    const int dA0 = wave * 1024;              // A dest base, dbuf0
    const int dB0 = 16384 + wave * 1024;      // B dest base, dbuf0

    // prologue: buf0 A+B (K-tile 0), buf1 B (K-tile 1); buf1-A staged in ph1-2
    STAGE2(gA00, gA01, dA0,                0);
    STAGE2(gA10, gA11, dA0 + 8192,         0);
    STAGE2(gB00, gB01, dB0,                0);
    STAGE2(gB10, gB11, dB0 + 8192,         0);
    STAGE2(gB00, gB01, dB0 + 32768,        64);
    STAGE2(gB10, gB11, dB0 + 32768 + 8192, 64);
    asm volatile("s_waitcnt vmcnt(4)" ::: "memory");
    PH_BAR;

    const int NIT = Dq / 128;                 // 16 iters, 2 K-tiles each
    for (int it = 0; it < NIT; ++it) {
        const bool pre = (it < NIT - 1);

        // ---- K-tile even (buf0) : phases 1-4 ----
        LDA(swA0k0, swA0k1, 0); LDB(swB0k0, swB0k1, 0);
        STAGE2(gA00, gA01, dA0 + 32768, 64);             // buf1-A h0 (this iter)
        asm volatile("s_waitcnt lgkmcnt(8)" ::: "memory");
        PH_BAR; PRIO1; MMA(0, 0); PRIO0; PH_BAR;

        LDB(swB0k0, swB0k1, 2);
        STAGE2(gA10, gA11, dA0 + 32768 + 8192, 64);      // buf1-A h1
        PH_BAR; PRIO1; MMA(0, 2); PRIO0; PH_BAR;

        LDA(swA0k0, swA0k1, 4);
        if (pre) STAGE2(gB00, gB01, dB0, 128);           // buf0-B h0 (next iter)
        PH_BAR; PRIO1; MMA(4, 0); PRIO0; PH_BAR;

        if (pre) {
            STAGE2(gB10, gB11, dB0 + 8192, 128);         // buf0-B h1
            asm volatile("s_waitcnt vmcnt(4)" ::: "memory");   // drains buf1 stages
        } else {
            asm volatile("s_waitcnt vmcnt(0)" ::: "memory");
        }
        PH_BAR; PRIO1; MMA(4, 2); PRIO0; PH_BAR;

        // ---- K-tile odd (buf1) : phases 5-8 ----
        LDA(swA1k0, swA1k1, 0); LDB(swB1k0, swB1k1, 0);
        if (pre) STAGE2(gA00, gA01, dA0, 128);           // buf0-A h0 (next iter)
        asm volatile("s_waitcnt lgkmcnt(8)" ::: "memory");
        PH_BAR; PRIO1; MMA(0, 0); PRIO0; PH_BAR;

        LDB(swB1k0, swB1k1, 2);
        if (pre) STAGE2(gA10, gA11, dA0 + 8192, 128);    // buf0-A h1
        PH_BAR; PRIO1; MMA(0, 2); PRIO0; PH_BAR;

        LDA(swA1k0, swA1k1, 4);
        if (pre) STAGE2(gB00, gB01, dB0 + 32768, 192);   // buf1-B h0 (next iter)
        PH_BAR; PRIO1; MMA(4, 0); PRIO0; PH_BAR;

        if (pre) {
            STAGE2(gB10, gB11, dB0 + 32768 + 8192, 192); // buf1-B h1
            asm volatile("s_waitcnt vmcnt(4)" ::: "memory");   // drains buf0 stages
        }
        PH_BAR; PRIO1; MMA(4, 2); PRIO0; PH_BAR;

        gA00 += 128; gA01 += 128; gA10 += 128; gA11 += 128;
        gB00 += 128; gB01 += 128; gB10 += 128; gB11 += 128;
    }

    // ---- epilogue phase A: sigmoid -> LDS (bf16, col ^ ((row>>2)&3)<<4) ----
#pragma unroll
    for (int fn = 0; fn < 4; ++fn) {
        const int col = wc * 64 + fn * 16 + rr;
        const float gb = gate_b[tn + col];
#pragma unroll
        for (int fm = 0; fm < 8; ++fm) {
#pragma unroll
            for (int j = 0; j < 4; ++j) {
                const int row = wr * 128 + fm * 16 + kq * 4 + j;   // (row>>2)&3 == kq
                const float logit = acc[fm][fn][j] + gb;
                const float sg = 1.0f / (1.0f + __expf(-logit));
                lds[row * 256 + (col ^ (kq << 4))] = f2bf(sg);
            }
        }
    }
    __syncthreads();

    // ---- epilogue phase B: coalesced u_g + fused per-chunk scan partials ---
    const int lr2  = lane >> 5;               // 0/1
    const int cb32 = lane & 31;
    const int c0   = cb32 * 8;                // 8-col segment
    const int baseT = wave * 2 + lr2;         // 0..15: row offset within 16
    const int cX = ((baseT >> 2) & 3) << 4;   // constant swizzle for this thread

    float bw[8], a16[8], w15[8];
    {
        const float* bp   = bvec + tn + c0;
        const float* a16p = aapow + 16 * Dq + tn + c0;
        const float* w15p = aapow + (15 - baseT) * Dq + tn + c0;
#pragma unroll
        for (int k = 0; k < 8; ++k) { bw[k] = bp[k]; a16[k] = a16p[k]; w15[k] = w15p[k]; }
    }

    float ps[2][8] = {}, cr[2][8] = {};
#pragma unroll
    for (int i = 0; i < 16; ++i) {
        const int r = baseT + i * 16;         // row in tile
        const int ck = i >> 3;                // local chunk (0/1)
        const long long gidx = (long long)(tm + r) * Dq + tn + c0;
        const bf16x8 u8 = *(const bf16x8*)&Abf[gidx];
        const bf16x8 s8 = *(const bf16x8*)&lds[r * 256 + (c0 ^ cX)];
        float ug[8];
#pragma unroll
        for (int k = 0; k < 8; ++k) {
            ug[k] = bf2f((unsigned short)u8[k]) * bf2f((unsigned short)s8[k]);
            ps[ck][k] += ug[k];
            cr[ck][k] = a16[k] * cr[ck][k] + bw[k] * ug[k];
        }
        if constexpr (UGBF) {
            us8 o;
#pragma unroll
            for (int k = 0; k < 8; ++k) o[k] = f2bf(ug[k]);
            *(us8*)&((unsigned short*)ug_)[gidx] = o;
        } else {
            f32x4 o0, o1;
            o0.x = ug[0]; o0.y = ug[1]; o0.z = ug[2]; o0.w = ug[3];
            o1.x = ug[4]; o1.y = ug[5]; o1.z = ug[6]; o1.w = ug[7];
            *(f32x4*)&((float*)ug_)[gidx]     = o0;
            *(f32x4*)&((float*)ug_)[gidx + 4] = o1;
        }
    }
    __syncthreads();                           // all sigma reads done

    // deterministic 16-slot tree reduce in LDS: red[p:4][col:256][slot:16] f32
    float* redf = (float*)lds;
    const int slot = (baseT + cb32) & 15;      // rotation: col>>3 == cb32
#pragma unroll
    for (int ck = 0; ck < 2; ++ck)
#pragma unroll
        for (int k = 0; k < 8; ++k) {
            const int col = c0 + k;
            redf[((ck * 2 + 0) * 256 + col) * 16 + slot] = ps[ck][k];
            redf[((ck * 2 + 1) * 256 + col) * 16 + slot] = cr[ck][k] * w15[k];
        }
    __syncthreads();

    const int bb  = tm >> 11;                  // batch index
    const int ckb = (tm & 2047) >> 7;          // global chunk base
#pragma unroll
    for (int ii = 0; ii < 2; ++ii) {
        const int item = tid + ii * 512;       // 1024 items = 4 groups x 256 cols
        const int p = item >> 8, col = item & 255;
        const int ck = p >> 1, isC = p & 1;
        const int rot = (item & 3) * 4;
        float s = 0.f;
#pragma unroll
        for (int q = 0; q < 4; ++q) {
            const f32x4 v = *(const f32x4*)&redf[item * 16 + ((rot + q * 4) & 15)];
            s += v.x + v.y + v.z + v.w;
        }
        const long long gi = (long long)(bb * NC + ckb + ck) * Dq + tn + col;
        if (isC) carry[gi] = s; else psum[gi] = s;
    }
}

// ---------------- K3: mean -> rank-4 projection -> d_eff --------------------
__global__ __launch_bounds__(256) void k3_deff(
    const float* __restrict__ psum, const float* __restrict__ dvec,
    const float* __restrict__ dlru, const float* __restrict__ dlrv,
    float* __restrict__ deff)
{
    const int bb = blockIdx.x, tid = threadIdx.x;
    __shared__ float red[4][256];
    __shared__ float proj[4];
    float pr[4] = {0.f, 0.f, 0.f, 0.f};
    for (int i = 0; i < Dq / 256; ++i) {
        int dd = tid + i * 256;
        float m = 0.f;
        for (int k = 0; k < NC; ++k) m += psum[((long long)bb * NC + k) * Dq + dd];
        m *= (1.0f / (float)Tq);
#pragma unroll
        for (int r = 0; r < 4; ++r) pr[r] += m * dlru[dd * Rq + r];
    }
#pragma unroll
    for (int r = 0; r < 4; ++r) red[r][tid] = pr[r];
    __syncthreads();
    for (int off = 128; off > 0; off >>= 1) {
        if (tid < off)
#pragma unroll
            for (int r = 0; r < 4; ++r) red[r][tid] += red[r][tid + off];
        __syncthreads();
    }
    if (tid < 4) proj[tid] = red[tid][0] * 0.25f;
    __syncthreads();
    float p0 = proj[0], p1 = proj[1], p2 = proj[2], p3 = proj[3];
    for (int i = 0; i < Dq / 256; ++i) {
        int e = tid + i * 256;
        float v = dvec[e] + p0 * dlrv[0 * Dq + e] + p1 * dlrv[1 * Dq + e]
                          + p2 * dlrv[2 * Dq + e] + p3 * dlrv[3 * Dq + e];
        deff[(long long)bb * Dq + e] = v;
    }
}

// ---------------- K4: scan pass C — combine carries, rescan, write y --------
template<int UGBF>
__global__ __launch_bounds__(128) void k4_scanC(
    const void* __restrict__ ug, float* __restrict__ yout,
    const float* __restrict__ aat, const float* __restrict__ aaLt,
    const float* __restrict__ bvec, const float* __restrict__ cvec,
    const float* __restrict__ deff, const float* __restrict__ carry)
{
    const int d0 = blockIdx.x * 512 + threadIdx.x * 4;
    const int ck = blockIdx.y, bb = blockIdx.z;
    f32x4 aa  = *(const f32x4*)&aat[d0];
    f32x4 aaL = *(const f32x4*)&aaLt[d0];
    f32x4 bv  = *(const f32x4*)&bvec[d0];
    f32x4 cv  = *(const f32x4*)&cvec[d0];
    f32x4 de  = *(const f32x4*)&deff[(long long)bb * Dq + d0];
    f32x4 s = {0.f, 0.f, 0.f, 0.f};
    for (int j = 0; j < ck; ++j) {
        f32x4 cj = *(const f32x4*)&carry[((long long)bb * NC + j) * Dq + d0];
        s = aaL * s + cj;
    }
    const long long base = ((long long)bb * Tq + (long long)ck * CL) * Dq + d0;
    for (int t = 0; t < CL; ++t) {
        f32x4 x = ld4<UGBF>(ug, base + (long long)t * Dq);
        s = aa * s + bv * x;
        f32x4 y = cv * s + de * x;
        *(f32x4*)&yout[base + (long long)t * Dq] = y;
    }
}

extern "C" void kernel_launch(void* const* d_in, const int* in_sizes, int n_in,
                              void* d_out, int out_size, void* d_ws, size_t ws_size,
                              hipStream_t stream)
{
    const float* u    = (const float*)d_in[0];
    const float* a    = (const float*)d_in[1];
    const float* b    = (const float*)d_in[2];
    const float* c    = (const float*)d_in[3];
    const float* d    = (const float*)d_in[4];
    const float* gw   = (const float*)d_in[5];
    const float* gb   = (const float*)d_in[6];
    const float* dlru = (const float*)d_in[7];
    const float* dlrv = (const float*)d_in[8];
    float* out = (float*)d_out;

    char* ws = (char*)d_ws;
    const size_t sz_ubf = (size_t)Mq * Dq * 2;          // 64 MiB
    const size_t sz_wbf = (size_t)Dq * Dq * 2;          // 8 MiB
    const size_t sz_ug  = (size_t)Mq * Dq * 2;          // 64 MiB (bf16 u_g)
    const size_t sz_ps  = (size_t)Bq * NC * Dq * 4;     // 1 MiB each

    unsigned short* ubf = (unsigned short*)ws;
    unsigned short* wbf = (unsigned short*)(ws + sz_ubf);

    const size_t tail_sz = 2 * sz_ps + (size_t)Bq * Dq * 4
                         + 2 * (size_t)Dq * 4 + (size_t)17 * Dq * 4;
    const size_t need_bf16 = sz_ubf + sz_wbf + sz_ug + tail_sz;
    const bool ugbf_mode = (ws_size >= need_bf16);

    char* rest = ws + sz_ubf + sz_wbf;
    unsigned short* ugbf = (unsigned short*)rest;
    char* tail = ugbf_mode ? (rest + sz_ug) : rest;
    float* psum  = (float*)tail;
    float* carry = psum  + (size_t)Bq * NC * Dq;
    float* deff  = carry + (size_t)Bq * NC * Dq;
    float* aat   = deff  + (size_t)Bq * Dq;
    float* aaLt  = aat   + Dq;
    float* aapow = aaLt  + Dq;                          // [17][Dq]

    k0_convert<<<2048, 256, 0, stream>>>(u, gw, a, ubf, wbf, aat, aaLt, aapow);

    dim3 g2(Dq / 512, NC, Bq);
    if (ugbf_mode) {
        k1_gemm<1><<<512, 512, 0, stream>>>(ubf, wbf, gb, b, aapow, psum, carry, ugbf);
        k3_deff<<<Bq, 256, 0, stream>>>(psum, d, dlru, dlrv, deff);
        k4_scanC<1><<<g2, 128, 0, stream>>>(ugbf, out, aat, aaLt, b, c, deff, carry);
    } else {
        k1_gemm<0><<<512, 512, 0, stream>>>(ubf, wbf, gb, b, aapow, psum, carry, out);
        k3_deff<<<Bq, 256, 0, stream>>>(psum, d, dlru, dlrv, deff);
        k4_scanC<0><<<g2, 128, 0, stream>>>(out, out, aat, aaLt, b, c, deff, carry);
    }
}